// Round 1
// baseline (331.556 us; speedup 1.0000x reference)
//
#include <hip/hip_runtime.h>

// Problem constants
#define RED    100000   // reduction dim = C*RF*L = 1*50*2000
#define TT     32       // timesteps (M)
#define KF     512      // features (N)
#define THRESH 10.0f
#define KWTA   16

// GEMM tiling
#define CHUNKS 125      // red-dim split
#define CHUNK  800      // 125*800 = 100000 exactly
#define RB     32       // red elems per LDS stage
#define NSTAGE 25       // CHUNK/RB
#define TN     128      // k-tile width
#define NKT    4        // KF/TN
#define BPAD   130      // padded LDS row for B (2-way-free transpose writes)

// ---------------------------------------------------------------------------
// K1: split-K GEMM. Each WG computes a full 32 x 128 tile over an 800-long
// reduction chunk. ATOMIC=0: write partial tile to ws. ATOMIC=1: atomicAdd
// into the 32x512 out-matrix (fallback when ws is too small).
// ---------------------------------------------------------------------------
template <int ATOMIC>
__global__ __launch_bounds__(256, 2)
void gemm_k(const float* __restrict__ rec, const float* __restrict__ wgt,
            float* __restrict__ dst) {
  __shared__ float Al[TT][RB];     // A staged row-major      (4 KB)
  __shared__ float Bl[RB][BPAD];   // B staged transposed     (~16.6 KB)

  const int chunk = blockIdx.x;    // 0..124
  const int kt    = blockIdx.y;    // 0..3
  const int tid   = threadIdx.x;
  const int wv    = tid >> 6;      // wave id: owns rows [8wv, 8wv+8)
  const int ln    = tid & 63;      // lane: owns cols {2ln, 2ln+1}
  const int t0    = tid >> 3;      // 0..31 staging row
  const int r4    = tid & 7;       // float4 slot within 32-wide red step

  const float* ap = rec + (size_t)t0 * RED + chunk * CHUNK + r4 * 4;
  const float* bp = wgt + (size_t)(kt * TN + t0) * RED + chunk * CHUNK + r4 * 4;
  const size_t bstride = (size_t)32 * RED;

  float acc[8][2];
#pragma unroll
  for (int j = 0; j < 8; ++j) { acc[j][0] = 0.f; acc[j][1] = 0.f; }

  // prefetch stage 0 into registers
  float4 av = *(const float4*)ap;
  float4 b0 = *(const float4*)(bp);
  float4 b1 = *(const float4*)(bp + bstride);
  float4 b2 = *(const float4*)(bp + 2 * bstride);
  float4 b3 = *(const float4*)(bp + 3 * bstride);

  for (int s = 0; s < NSTAGE; ++s) {
    __syncthreads();                       // prev compute done reading LDS
    *(float4*)&Al[t0][r4 * 4] = av;
    {
      const int rr = r4 * 4;
#pragma unroll
      for (int j = 0; j < 4; ++j) {        // transpose B into [r][k]
        Bl[rr + j][t0     ] = ((const float*)&b0)[j];
        Bl[rr + j][t0 + 32] = ((const float*)&b1)[j];
        Bl[rr + j][t0 + 64] = ((const float*)&b2)[j];
        Bl[rr + j][t0 + 96] = ((const float*)&b3)[j];
      }
    }
    __syncthreads();
    if (s + 1 < NSTAGE) {                  // issue next-stage loads early:
      ap += RB; bp += RB;                  // HBM latency hides under compute
      av = *(const float4*)ap;
      b0 = *(const float4*)(bp);
      b1 = *(const float4*)(bp + bstride);
      b2 = *(const float4*)(bp + 2 * bstride);
      b3 = *(const float4*)(bp + 3 * bstride);
    }
#pragma unroll
    for (int r = 0; r < RB; ++r) {
      const float2 b = *(const float2*)&Bl[r][2 * ln];   // min-round, ~conflict-free
#pragma unroll
      for (int j = 0; j < 8; ++j) {
        const float a = Al[wv * 8 + j][r];               // wave-uniform -> broadcast
        acc[j][0] = fmaf(a, b.x, acc[j][0]);
        acc[j][1] = fmaf(a, b.y, acc[j][1]);
      }
    }
  }

  if (ATOMIC) {
#pragma unroll
    for (int j = 0; j < 8; ++j) {
      const int t = wv * 8 + j;
      const int kg = kt * TN + 2 * ln;
      atomicAdd(&dst[t * KF + kg    ], acc[j][0]);
      atomicAdd(&dst[t * KF + kg + 1], acc[j][1]);
    }
  } else {
    float* p = dst + (size_t)(chunk * NKT + kt) * TT * TN;
#pragma unroll
    for (int j = 0; j < 8; ++j) {
      *(float2*)&p[(wv * 8 + j) * TN + 2 * ln] = make_float2(acc[j][0], acc[j][1]);
    }
  }
}

// ---------------------------------------------------------------------------
// K2: reduce 125 partial tiles -> out-matrix om[32][512]
// partial layout: [chunk][kt][t][kk]
// ---------------------------------------------------------------------------
__global__ __launch_bounds__(256)
void reduce_k(const float* __restrict__ part, float* __restrict__ om) {
  const int i  = blockIdx.x * 256 + threadIdx.x;  // 0..16383
  const int t  = i >> 9;
  const int k  = i & 511;
  const int kt = k >> 7;
  const int kk = k & 127;
  const float* p = part + (size_t)kt * TT * TN + (size_t)t * TN + kk;
  float s = 0.f;
  for (int c = 0; c < CHUNKS; ++c) s += p[(size_t)c * NKT * TT * TN];
  om[i] = s;
}

// ---------------------------------------------------------------------------
// K3: threshold / nspk / first-spike value / v / total / 16x KWTA argmax /
// final sign mask. One 512-thread workgroup; om may alias d_out.
// ---------------------------------------------------------------------------
__global__ __launch_bounds__(512)
void kwta_k(const float* __restrict__ om, float* __restrict__ out) {
  __shared__ float tot[KF];
  __shared__ float redv[KF];
  __shared__ int   redi[KF];
  __shared__ float coef[KF];
  const int k = threadIdx.x;   // 0..511, one feature per thread

  int ns = 0;
#pragma unroll
  for (int t = 0; t < TT; ++t) ns += (om[t * KF + k] > THRESH) ? 1 : 0;
  int first = TT - ns;                 // ns in [0,32] -> first in [0,32]
  if (first > TT - 1) first = TT - 1;  // clip to 31
  float pf = om[first * KF + k];
  pf = (pf > THRESH) ? pf : 0.0f;      // pot at "first spike" row

  // v = max_k(values * sign(nspk)) * T  via block max-reduce
  redv[k] = (ns > 0) ? pf : 0.0f;
  __syncthreads();
  for (int s = 256; s >= 1; s >>= 1) {
    if (k < s) redv[k] = fmaxf(redv[k], redv[k + s]);
    __syncthreads();
  }
  const float v = redv[0] * (float)TT;

  // total = nspk*values + nspk*v  (two rounded products, like the reference)
  const float t1 = (float)ns * pf;
  const float t2 = (float)ns * v;
  tot[k]  = t1 + t2;                   // total >= 0 always
  coef[k] = 0.0f;
  __syncthreads();

  // KWTA: 16 iterations of first-index argmax; suppress winner
  for (int it = 0; it < KWTA; ++it) {
    redv[k] = tot[k];
    redi[k] = k;
    __syncthreads();
    for (int s = 256; s >= 1; s >>= 1) {
      if (k < s) {
        const float a = redv[k], b = redv[k + s];
        if (b > a || (b == a && redi[k + s] < redi[k])) {
          redv[k] = b; redi[k] = redi[k + s];
        }
      }
      __syncthreads();
    }
    const float mx = redv[0];
    const int   wi = redi[0];
    if (mx == 0.0f) break;             // uniform decision: remaining winners = -1
    if (k == 0) { tot[wi] = 0.0f; coef[wi] = 1.0f; }
    __syncthreads();
  }
  __syncthreads();

  // out = sign(pot * coef), shape (T,K,1,1) flattened
  for (int i = k; i < TT * KF; i += KF) {
    const int kk = i & 511;
    const float p = om[i];
    out[i] = (p > THRESH && coef[kk] != 0.0f) ? 1.0f : 0.0f;
  }
}

// ---------------------------------------------------------------------------
extern "C" void kernel_launch(void* const* d_in, const int* in_sizes, int n_in,
                              void* d_out, int out_size, void* d_ws, size_t ws_size,
                              hipStream_t stream) {
  const float* rec = (const float*)d_in[0];   // (32,1,50,2000)
  const float* wgt = (const float*)d_in[1];   // (512,1,50,2000)
  float* out = (float*)d_out;                 // 16384 floats
  float* om  = (float*)d_out;                 // out-matrix scratch aliases d_out
                                              // (fully overwritten by K3 last pass)
  const size_t part_bytes = (size_t)CHUNKS * NKT * TT * TN * sizeof(float); // 8.192 MB

  if (ws_size >= part_bytes) {
    float* part = (float*)d_ws;
    gemm_k<0><<<dim3(CHUNKS, NKT), 256, 0, stream>>>(rec, wgt, part);
    reduce_k<<<(TT * KF) / 256, 256, 0, stream>>>(part, om);
  } else {
    hipMemsetAsync(om, 0, (size_t)TT * KF * sizeof(float), stream);
    gemm_k<1><<<dim3(CHUNKS, NKT), 256, 0, stream>>>(rec, wgt, om);
  }
  kwta_k<<<1, 512, 0, stream>>>(om, out);
}